// Round 2
// baseline (3823.166 us; speedup 1.0000x reference)
//
#include <hip/hip_runtime.h>
#include <hip/hip_bf16.h>
#include <math.h>

// ---------------------------------------------------------------------------
// GAT 2-layer network on MI355X.
// CSR (by dst) built once per launch; per time step:
//   GEMM1(+att dots) -> edge-softmax-agg(+ELU) -> GEMM2(+att dots)
//   -> edge-softmax-agg(+log_softmax).
// Edge aggregation: one wave per dst node, flash-style online softmax with
// 8-wide edge chunking for memory-level parallelism (latency was the limit).
// ---------------------------------------------------------------------------

// ---- CSR construction ------------------------------------------------------

__global__ __launch_bounds__(256) void init_cnt_kernel(int* cnt, int N) {
    int i = blockIdx.x * 256 + threadIdx.x;
    if (i < N) cnt[i] = 1;  // self-loop contributes 1 to every node
}

__global__ __launch_bounds__(256) void count_edges_kernel(const int* __restrict__ dsts,
                                                          int* cnt, int E) {
    int i = blockIdx.x * 256 + threadIdx.x;
    if (i < E) atomicAdd(&cnt[dsts[i]], 1);
}

__global__ __launch_bounds__(1024) void scan_kernel(const int* __restrict__ cnt,
                                                    int* row, int* cur, int N) {
    __shared__ int ls[1024];
    int t = threadIdx.x;
    int chunk = (N + 1023) / 1024;
    int b = t * chunk;
    int sum = 0;
    for (int i = 0; i < chunk; ++i) {
        int idx = b + i;
        if (idx < N) sum += cnt[idx];
    }
    ls[t] = sum;
    __syncthreads();
    for (int off = 1; off < 1024; off <<= 1) {
        int v = (t >= off) ? ls[t - off] : 0;
        __syncthreads();
        ls[t] += v;
        __syncthreads();
    }
    int run = (t == 0) ? 0 : ls[t - 1];
    for (int i = 0; i < chunk; ++i) {
        int idx = b + i;
        if (idx < N) {
            int c = cnt[idx];
            row[idx] = run;
            cur[idx] = run;
            run += c;
        }
    }
    if (t == 1023) row[N] = ls[1023];
}

__global__ __launch_bounds__(256) void fill_csr_kernel(const int* __restrict__ srcs,
                                                       const int* __restrict__ dsts,
                                                       int* cur, int* esrc, int E, int N) {
    int i = blockIdx.x * 256 + threadIdx.x;
    if (i >= E + N) return;
    int s, d;
    if (i < E) { s = srcs[i]; d = dsts[i]; }
    else       { s = i - E;   d = s; }      // self-loops appended
    int pos = atomicAdd(&cur[d], 1);
    esrc[pos] = s;
}

// ---- GEMM (h = x@W) fused with attention dot-products ----------------------
// Each wave: 8 rows, W column in 64 registers/lane, float4 broadcast x loads,
// 8 independent accumulator chains.

template <int H, int C>
__global__ __launch_bounds__(256) void gemm_att_kernel(
    const float* __restrict__ xin,   // [N,64]
    const float* __restrict__ Wm,    // [64,64]  h[n,c] = sum_k x[n,k]*W[k,c]
    const float* __restrict__ att_s, // [H*C]
    const float* __restrict__ att_d, // [H*C]
    float* __restrict__ hout,        // [N,64]
    float* __restrict__ asrc,        // [N*H]
    float* __restrict__ adst,        // [N*H]
    int N) {
    int tid = threadIdx.x;
    int c   = tid & 63;
    int wv  = tid >> 6;          // wave 0..3
    int base = blockIdx.x * 32;
    int r0   = wv * 8;           // this wave's first row (within block)

    float wreg[64];
#pragma unroll
    for (int k = 0; k < 64; ++k) wreg[k] = Wm[k * 64 + c];

    const float4* xrow[8];
#pragma unroll
    for (int r = 0; r < 8; ++r) {
        int n = base + r0 + r;
        if (n >= N) n = N - 1;               // clamp (redundant read, store guarded)
        xrow[r] = (const float4*)(xin + (size_t)n * 64);
    }

    float acc[8];
#pragma unroll
    for (int r = 0; r < 8; ++r) acc[r] = 0.f;

#pragma unroll
    for (int k4 = 0; k4 < 16; ++k4) {
        float4 xv[8];
#pragma unroll
        for (int r = 0; r < 8; ++r) xv[r] = xrow[r][k4];
#pragma unroll
        for (int r = 0; r < 8; ++r) {
            acc[r] = fmaf(xv[r].x, wreg[4 * k4 + 0], acc[r]);
            acc[r] = fmaf(xv[r].y, wreg[4 * k4 + 1], acc[r]);
            acc[r] = fmaf(xv[r].z, wreg[4 * k4 + 2], acc[r]);
            acc[r] = fmaf(xv[r].w, wreg[4 * k4 + 3], acc[r]);
        }
    }

    float as_w = att_s[c];
    float ad_w = att_d[c];
#pragma unroll
    for (int r = 0; r < 8; ++r) {
        int n = base + r0 + r;
        if (n >= N) break;
        float a = acc[r];
        hout[(size_t)n * 64 + c] = a;
        float vs = a * as_w;
        float vd = a * ad_w;
#pragma unroll
        for (int off = 1; off < C; off <<= 1) {
            vs += __shfl_xor(vs, off, 64);
            vd += __shfl_xor(vd, off, 64);
        }
        if ((c % C) == 0) {
            int hd = c / C;
            asrc[(size_t)n * H + hd] = vs;
            adst[(size_t)n * H + hd] = vd;
        }
    }
}

// ---- Edge-softmax aggregation (one wave per dst node, 8-wide chunks) -------

template <int H, int C, bool FINAL>
__global__ __launch_bounds__(256) void gat_edge_kernel(
    const float* __restrict__ h,     // [N,64]
    const float* __restrict__ asrc,  // [N*H]
    const float* __restrict__ adst,  // [N*H]
    const int* __restrict__ row,     // [N+1]
    const int* __restrict__ esrc,    // [Etot]
    const float* __restrict__ bias,  // [64]
    float* __restrict__ out,         // [N,64]
    int N) {
    int tid  = threadIdx.x;
    int lane = tid & 63;
    int n    = blockIdx.x * 4 + (tid >> 6);
    if (n >= N) return;

    int hd = lane / C;
    float adn = adst[(size_t)n * H + hd];
    int e0 = row[n], e1 = row[n + 1];

    float m = -INFINITY, lsum = 0.f, acc = 0.f;
    for (int e = e0; e < e1; e += 8) {
        int s[8];
#pragma unroll
        for (int j = 0; j < 8; ++j) {
            int ee = e + j;
            s[j] = (ee < e1) ? esrc[ee] : 0;
        }
        float hv[8];
#pragma unroll
        for (int j = 0; j < 8; ++j) hv[j] = h[(size_t)s[j] * 64 + lane];
        float al[8];
#pragma unroll
        for (int j = 0; j < 8; ++j) {
            float a = asrc[(size_t)s[j] * H + hd] + adn;
            a = a > 0.f ? a : 0.2f * a;                  // leaky_relu(0.2)
            al[j] = (e + j < e1) ? a : -INFINITY;
        }
        float cm = al[0];
#pragma unroll
        for (int j = 1; j < 8; ++j) cm = fmaxf(cm, al[j]);
        float mn    = fmaxf(m, cm);
        float scale = __expf(m - mn);                    // first chunk: exp(-inf)=0
        float ps = 0.f, pa = 0.f;
#pragma unroll
        for (int j = 0; j < 8; ++j) {
            float p = __expf(al[j] - mn);                // padded: exp(-inf)=0
            ps += p;
            pa = fmaf(p, hv[j], pa);
        }
        lsum = lsum * scale + ps;
        acc  = acc * scale + pa;
        m = mn;
    }

    float v = acc / (lsum + 1e-16f) + bias[lane];
    if (!FINAL) {
        out[(size_t)n * 64 + lane] = v > 0.f ? v : expm1f(v);   // ELU
    } else {
        float mx = v;
#pragma unroll
        for (int off = 1; off < 64; off <<= 1) mx = fmaxf(mx, __shfl_xor(mx, off, 64));
        float ex = __expf(v - mx);
        float sm = ex;
#pragma unroll
        for (int off = 1; off < 64; off <<= 1) sm += __shfl_xor(sm, off, 64);
        out[(size_t)n * 64 + lane] = (v - mx) - __logf(sm);
    }
}

// ---------------------------------------------------------------------------

extern "C" void kernel_launch(void* const* d_in, const int* in_sizes, int n_in,
                              void* d_out, int out_size, void* d_ws, size_t ws_size,
                              hipStream_t stream) {
    const float* x        = (const float*)d_in[0];   // [T,N,64]
    const int*   eidx     = (const int*)d_in[1];     // [2,E]
    const float* W1       = (const float*)d_in[2];
    const float* att_src1 = (const float*)d_in[3];
    const float* att_dst1 = (const float*)d_in[4];
    const float* bias1    = (const float*)d_in[5];
    const float* W2       = (const float*)d_in[6];
    const float* att_src2 = (const float*)d_in[7];
    const float* att_dst2 = (const float*)d_in[8];
    const float* bias2    = (const float*)d_in[9];
    float* dout = (float*)d_out;

    const int N = 50000;
    const int F = 64;
    const int E = in_sizes[1] / 2;
    const int T = in_sizes[0] / (N * F);
    const int Etot = E + N;

    const int* srcs = eidx;
    const int* dsts = eidx + E;

    char* ws = (char*)d_ws;
    size_t off = 0;
    auto carve = [&](size_t bytes) -> void* {
        void* p = ws + off;
        off = (off + bytes + 255) & ~(size_t)255;
        return p;
    };
    float* h_buf = (float*)carve((size_t)N * 64 * sizeof(float));
    float* y1    = (float*)carve((size_t)N * 64 * sizeof(float));
    float* asrc  = (float*)carve((size_t)N * 8 * sizeof(float));
    float* adst  = (float*)carve((size_t)N * 8 * sizeof(float));
    int*   rowp  = (int*)carve((size_t)(N + 1) * sizeof(int));
    int*   cnt   = (int*)carve((size_t)N * sizeof(int));
    int*   cur   = (int*)carve((size_t)N * sizeof(int));
    int*   esrc  = (int*)carve((size_t)Etot * sizeof(int));
    (void)ws_size;

    init_cnt_kernel<<<(N + 255) / 256, 256, 0, stream>>>(cnt, N);
    count_edges_kernel<<<(E + 255) / 256, 256, 0, stream>>>(dsts, cnt, E);
    scan_kernel<<<1, 1024, 0, stream>>>(cnt, rowp, cur, N);
    fill_csr_kernel<<<(E + N + 255) / 256, 256, 0, stream>>>(srcs, dsts, cur, esrc, E, N);

    int gemm_grid = (N + 31) / 32;
    int edge_grid = (N + 3) / 4;
    for (int t = 0; t < T; ++t) {
        const float* xt = x + (size_t)t * N * F;
        float* ot = dout + (size_t)t * N * F;

        gemm_att_kernel<8, 8><<<gemm_grid, 256, 0, stream>>>(
            xt, W1, att_src1, att_dst1, h_buf, asrc, adst, N);
        gat_edge_kernel<8, 8, false><<<edge_grid, 256, 0, stream>>>(
            h_buf, asrc, adst, rowp, esrc, bias1, y1, N);
        gemm_att_kernel<1, 64><<<gemm_grid, 256, 0, stream>>>(
            y1, W2, att_src2, att_dst2, h_buf, asrc, adst, N);
        gat_edge_kernel<1, 64, true><<<edge_grid, 256, 0, stream>>>(
            h_buf, asrc, adst, rowp, esrc, bias2, ot, N);
    }
}

// Round 3
// 2532.691 us; speedup vs baseline: 1.5095x; 1.5095x over previous
//
#include <hip/hip_runtime.h>
#include <hip/hip_bf16.h>
#include <math.h>

// ---------------------------------------------------------------------------
// GAT 2-layer network on MI355X.
// CSR (by dst) built once per launch; per time step:
//   GEMM1(+att dots) -> edge-softmax-agg(+ELU) -> GEMM2(+att dots)
//   -> edge-softmax-agg(+log_softmax).
// GEMM: W staged in LDS, 4 rows/wave (4 indep acc chains), ~45 VGPR for
// full occupancy. Edge agg: one wave per dst node, flash-style online
// softmax, 16-wide edge chunks for memory-level parallelism.
// ---------------------------------------------------------------------------

// ---- CSR construction ------------------------------------------------------

__global__ __launch_bounds__(256) void init_cnt_kernel(int* cnt, int N) {
    int i = blockIdx.x * 256 + threadIdx.x;
    if (i < N) cnt[i] = 1;  // self-loop contributes 1 to every node
}

__global__ __launch_bounds__(256) void count_edges_kernel(const int* __restrict__ dsts,
                                                          int* cnt, int E) {
    int i = blockIdx.x * 256 + threadIdx.x;
    if (i < E) atomicAdd(&cnt[dsts[i]], 1);
}

__global__ __launch_bounds__(1024) void scan_kernel(const int* __restrict__ cnt,
                                                    int* row, int* cur, int N) {
    __shared__ int ls[1024];
    int t = threadIdx.x;
    int chunk = (N + 1023) / 1024;
    int b = t * chunk;
    int sum = 0;
    for (int i = 0; i < chunk; ++i) {
        int idx = b + i;
        if (idx < N) sum += cnt[idx];
    }
    ls[t] = sum;
    __syncthreads();
    for (int off = 1; off < 1024; off <<= 1) {
        int v = (t >= off) ? ls[t - off] : 0;
        __syncthreads();
        ls[t] += v;
        __syncthreads();
    }
    int run = (t == 0) ? 0 : ls[t - 1];
    for (int i = 0; i < chunk; ++i) {
        int idx = b + i;
        if (idx < N) {
            int c = cnt[idx];
            row[idx] = run;
            cur[idx] = run;
            run += c;
        }
    }
    if (t == 1023) row[N] = ls[1023];
}

__global__ __launch_bounds__(256) void fill_csr_kernel(const int* __restrict__ srcs,
                                                       const int* __restrict__ dsts,
                                                       int* cur, int* esrc, int E, int N) {
    int i = blockIdx.x * 256 + threadIdx.x;
    if (i >= E + N) return;
    int s, d;
    if (i < E) { s = srcs[i]; d = dsts[i]; }
    else       { s = i - E;   d = s; }      // self-loops appended
    int pos = atomicAdd(&cur[d], 1);
    esrc[pos] = s;
}

// ---- GEMM (h = x@W) fused with attention dot-products ----------------------
// W in LDS (16KB). 4 rows per wave, lane c = output column. 4 independent
// FMA chains; x rows read as broadcast float4. 16 rows per block, grid=N/16.

template <int H, int C>
__global__ __launch_bounds__(256) void gemm_att_kernel(
    const float* __restrict__ xin,   // [N,64]
    const float* __restrict__ Wm,    // [64,64]  h[n,c] = sum_k x[n,k]*W[k,c]
    const float* __restrict__ att_s, // [H*C]
    const float* __restrict__ att_d, // [H*C]
    float* __restrict__ hout,        // [N,64]
    float* __restrict__ asrc,        // [N*H]
    float* __restrict__ adst,        // [N*H]
    int N) {
    __shared__ float Ws[64 * 64];
    int tid = threadIdx.x;
    {
        const float4* W4 = (const float4*)Wm;
        float4* Ws4 = (float4*)Ws;
#pragma unroll
        for (int i = 0; i < 4; ++i) Ws4[tid + 256 * i] = W4[tid + 256 * i];
    }
    __syncthreads();

    int c  = tid & 63;
    int wv = tid >> 6;
    int n0 = (blockIdx.x * 4 + wv) * 4;          // first of this wave's 4 rows
    if (n0 >= N) return;
    int nrows = (N - n0 >= 4) ? 4 : (N - n0);

    const float* xb = xin + (size_t)n0 * 64;
    float acc[4] = {0.f, 0.f, 0.f, 0.f};

#pragma unroll 2
    for (int k4 = 0; k4 < 16; ++k4) {
        float4 xv[4];
#pragma unroll
        for (int r = 0; r < 4; ++r) {
            int rr = (r < nrows) ? r : 0;
            xv[r] = *(const float4*)(xb + (size_t)rr * 64 + k4 * 4);
        }
        float w0 = Ws[(4 * k4 + 0) * 64 + c];
        float w1 = Ws[(4 * k4 + 1) * 64 + c];
        float w2 = Ws[(4 * k4 + 2) * 64 + c];
        float w3 = Ws[(4 * k4 + 3) * 64 + c];
#pragma unroll
        for (int r = 0; r < 4; ++r) {
            acc[r] = fmaf(xv[r].x, w0, acc[r]);
            acc[r] = fmaf(xv[r].y, w1, acc[r]);
            acc[r] = fmaf(xv[r].z, w2, acc[r]);
            acc[r] = fmaf(xv[r].w, w3, acc[r]);
        }
    }

    float as_w = att_s[c];
    float ad_w = att_d[c];
#pragma unroll
    for (int r = 0; r < 4; ++r) {
        if (r >= nrows) break;
        int n = n0 + r;
        float a = acc[r];
        hout[(size_t)n * 64 + c] = a;
        float vs = a * as_w;
        float vd = a * ad_w;
#pragma unroll
        for (int off = 1; off < C; off <<= 1) {
            vs += __shfl_xor(vs, off, 64);
            vd += __shfl_xor(vd, off, 64);
        }
        if ((c % C) == 0) {
            int hd = c / C;
            asrc[(size_t)n * H + hd] = vs;
            adst[(size_t)n * H + hd] = vd;
        }
    }
}

// ---- Edge-softmax aggregation (one wave per dst node, 16-wide chunks) ------

template <int H, int C, bool FINAL>
__global__ __launch_bounds__(256) void gat_edge_kernel(
    const float* __restrict__ h,     // [N,64]
    const float* __restrict__ asrc,  // [N*H]
    const float* __restrict__ adst,  // [N*H]
    const int* __restrict__ row,     // [N+1]
    const int* __restrict__ esrc,    // [Etot]
    const float* __restrict__ bias,  // [64]
    float* __restrict__ out,         // [N,64]
    int N) {
    int tid  = threadIdx.x;
    int lane = tid & 63;
    int n    = blockIdx.x * 4 + (tid >> 6);
    if (n >= N) return;

    int hd = lane / C;
    float adn = adst[(size_t)n * H + hd];
    int e0 = row[n], e1 = row[n + 1];

    float m = -INFINITY, lsum = 0.f, acc = 0.f;
    for (int e = e0; e < e1; e += 16) {
        int s[16];
#pragma unroll
        for (int j = 0; j < 16; ++j) {
            int ee = e + j;
            s[j] = (ee < e1) ? esrc[ee] : 0;
        }
        float hv[16];
#pragma unroll
        for (int j = 0; j < 16; ++j) hv[j] = h[(size_t)s[j] * 64 + lane];
        float al[16];
#pragma unroll
        for (int j = 0; j < 16; ++j) {
            float a = asrc[(size_t)s[j] * H + hd] + adn;
            a = a > 0.f ? a : 0.2f * a;                  // leaky_relu(0.2)
            al[j] = (e + j < e1) ? a : -INFINITY;
        }
        float cm = al[0];
#pragma unroll
        for (int j = 1; j < 16; ++j) cm = fmaxf(cm, al[j]);
        float mn    = fmaxf(m, cm);
        float scale = __expf(m - mn);                    // first chunk: exp(-inf)=0
        float ps = 0.f, pa = 0.f;
#pragma unroll
        for (int j = 0; j < 16; ++j) {
            float p = __expf(al[j] - mn);                // padded: exp(-inf)=0
            ps += p;
            pa = fmaf(p, hv[j], pa);
        }
        lsum = lsum * scale + ps;
        acc  = acc * scale + pa;
        m = mn;
    }

    float v = acc / (lsum + 1e-16f) + bias[lane];
    if (!FINAL) {
        out[(size_t)n * 64 + lane] = v > 0.f ? v : expm1f(v);   // ELU
    } else {
        float mx = v;
#pragma unroll
        for (int off = 1; off < 64; off <<= 1) mx = fmaxf(mx, __shfl_xor(mx, off, 64));
        float ex = __expf(v - mx);
        float sm = ex;
#pragma unroll
        for (int off = 1; off < 64; off <<= 1) sm += __shfl_xor(sm, off, 64);
        out[(size_t)n * 64 + lane] = (v - mx) - __logf(sm);
    }
}

// ---------------------------------------------------------------------------

extern "C" void kernel_launch(void* const* d_in, const int* in_sizes, int n_in,
                              void* d_out, int out_size, void* d_ws, size_t ws_size,
                              hipStream_t stream) {
    const float* x        = (const float*)d_in[0];   // [T,N,64]
    const int*   eidx     = (const int*)d_in[1];     // [2,E]
    const float* W1       = (const float*)d_in[2];
    const float* att_src1 = (const float*)d_in[3];
    const float* att_dst1 = (const float*)d_in[4];
    const float* bias1    = (const float*)d_in[5];
    const float* W2       = (const float*)d_in[6];
    const float* att_src2 = (const float*)d_in[7];
    const float* att_dst2 = (const float*)d_in[8];
    const float* bias2    = (const float*)d_in[9];
    float* dout = (float*)d_out;

    const int N = 50000;
    const int F = 64;
    const int E = in_sizes[1] / 2;
    const int T = in_sizes[0] / (N * F);
    const int Etot = E + N;

    const int* srcs = eidx;
    const int* dsts = eidx + E;

    char* ws = (char*)d_ws;
    size_t off = 0;
    auto carve = [&](size_t bytes) -> void* {
        void* p = ws + off;
        off = (off + bytes + 255) & ~(size_t)255;
        return p;
    };
    float* h_buf = (float*)carve((size_t)N * 64 * sizeof(float));
    float* y1    = (float*)carve((size_t)N * 64 * sizeof(float));
    float* asrc  = (float*)carve((size_t)N * 8 * sizeof(float));
    float* adst  = (float*)carve((size_t)N * 8 * sizeof(float));
    int*   rowp  = (int*)carve((size_t)(N + 1) * sizeof(int));
    int*   cnt   = (int*)carve((size_t)N * sizeof(int));
    int*   cur   = (int*)carve((size_t)N * sizeof(int));
    int*   esrc  = (int*)carve((size_t)Etot * sizeof(int));
    (void)ws_size;

    init_cnt_kernel<<<(N + 255) / 256, 256, 0, stream>>>(cnt, N);
    count_edges_kernel<<<(E + 255) / 256, 256, 0, stream>>>(dsts, cnt, E);
    scan_kernel<<<1, 1024, 0, stream>>>(cnt, rowp, cur, N);
    fill_csr_kernel<<<(E + N + 255) / 256, 256, 0, stream>>>(srcs, dsts, cur, esrc, E, N);

    int gemm_grid = (N + 15) / 16;
    int edge_grid = (N + 3) / 4;
    for (int t = 0; t < T; ++t) {
        const float* xt = x + (size_t)t * N * F;
        float* ot = dout + (size_t)t * N * F;

        gemm_att_kernel<8, 8><<<gemm_grid, 256, 0, stream>>>(
            xt, W1, att_src1, att_dst1, h_buf, asrc, adst, N);
        gat_edge_kernel<8, 8, false><<<edge_grid, 256, 0, stream>>>(
            h_buf, asrc, adst, rowp, esrc, bias1, y1, N);
        gemm_att_kernel<1, 64><<<gemm_grid, 256, 0, stream>>>(
            y1, W2, att_src2, att_dst2, h_buf, asrc, adst, N);
        gat_edge_kernel<1, 64, true><<<edge_grid, 256, 0, stream>>>(
            h_buf, asrc, adst, rowp, esrc, bias2, ot, N);
    }
}

// Round 4
// 2348.054 us; speedup vs baseline: 1.6282x; 1.0786x over previous
//
#include <hip/hip_runtime.h>
#include <hip/hip_bf16.h>
#include <math.h>

// ---------------------------------------------------------------------------
// GAT 2-layer network on MI355X.
// CSR (by dst) built once per launch; per time step:
//   GEMM1(+att dots) -> edge-softmax-agg(+ELU) -> GEMM2(+att dots)
//   -> edge-softmax-agg(+log_softmax).
// GEMM: W staged in LDS, 4 rows/wave. Edge agg: one wave per dst node,
// flash-style online softmax, 16-wide edge chunks for MLP.
// Feature table h stored in BF16: halves gather bytes (256->128 B/edge) and
// halves the gather working set (12.8->6.4 MB) for L2 residency. Attention
// scores and all accumulation stay f32.
// ---------------------------------------------------------------------------

typedef __hip_bfloat16 bf16;

// ---- CSR construction ------------------------------------------------------

__global__ __launch_bounds__(256) void init_cnt_kernel(int* cnt, int N) {
    int i = blockIdx.x * 256 + threadIdx.x;
    if (i < N) cnt[i] = 1;  // self-loop contributes 1 to every node
}

__global__ __launch_bounds__(256) void count_edges_kernel(const int* __restrict__ dsts,
                                                          int* cnt, int E) {
    int i = blockIdx.x * 256 + threadIdx.x;
    if (i < E) atomicAdd(&cnt[dsts[i]], 1);
}

__global__ __launch_bounds__(1024) void scan_kernel(const int* __restrict__ cnt,
                                                    int* row, int* cur, int N) {
    __shared__ int ls[1024];
    int t = threadIdx.x;
    int chunk = (N + 1023) / 1024;
    int b = t * chunk;
    int sum = 0;
    for (int i = 0; i < chunk; ++i) {
        int idx = b + i;
        if (idx < N) sum += cnt[idx];
    }
    ls[t] = sum;
    __syncthreads();
    for (int off = 1; off < 1024; off <<= 1) {
        int v = (t >= off) ? ls[t - off] : 0;
        __syncthreads();
        ls[t] += v;
        __syncthreads();
    }
    int run = (t == 0) ? 0 : ls[t - 1];
    for (int i = 0; i < chunk; ++i) {
        int idx = b + i;
        if (idx < N) {
            int c = cnt[idx];
            row[idx] = run;
            cur[idx] = run;
            run += c;
        }
    }
    if (t == 1023) row[N] = ls[1023];
}

__global__ __launch_bounds__(256) void fill_csr_kernel(const int* __restrict__ srcs,
                                                       const int* __restrict__ dsts,
                                                       int* cur, int* esrc, int E, int N) {
    int i = blockIdx.x * 256 + threadIdx.x;
    if (i >= E + N) return;
    int s, d;
    if (i < E) { s = srcs[i]; d = dsts[i]; }
    else       { s = i - E;   d = s; }      // self-loops appended
    int pos = atomicAdd(&cur[d], 1);
    esrc[pos] = s;
}

// ---- GEMM (h = x@W) fused with attention dot-products ----------------------
// W in LDS (16KB). 4 rows per wave, lane c = output column. h stored bf16;
// a_src/a_dst computed from the unrounded f32 accumulator.

template <int H, int C>
__global__ __launch_bounds__(256) void gemm_att_kernel(
    const float* __restrict__ xin,   // [N,64]
    const float* __restrict__ Wm,    // [64,64]  h[n,c] = sum_k x[n,k]*W[k,c]
    const float* __restrict__ att_s, // [H*C]
    const float* __restrict__ att_d, // [H*C]
    bf16* __restrict__ hout,         // [N,64] bf16
    float* __restrict__ asrc,        // [N*H]
    float* __restrict__ adst,        // [N*H]
    int N) {
    __shared__ float Ws[64 * 64];
    int tid = threadIdx.x;
    {
        const float4* W4 = (const float4*)Wm;
        float4* Ws4 = (float4*)Ws;
#pragma unroll
        for (int i = 0; i < 4; ++i) Ws4[tid + 256 * i] = W4[tid + 256 * i];
    }
    __syncthreads();

    int c  = tid & 63;
    int wv = tid >> 6;
    int n0 = (blockIdx.x * 4 + wv) * 4;          // first of this wave's 4 rows
    if (n0 >= N) return;
    int nrows = (N - n0 >= 4) ? 4 : (N - n0);

    const float* xb = xin + (size_t)n0 * 64;
    float acc[4] = {0.f, 0.f, 0.f, 0.f};

#pragma unroll 2
    for (int k4 = 0; k4 < 16; ++k4) {
        float4 xv[4];
#pragma unroll
        for (int r = 0; r < 4; ++r) {
            int rr = (r < nrows) ? r : 0;
            xv[r] = *(const float4*)(xb + (size_t)rr * 64 + k4 * 4);
        }
        float w0 = Ws[(4 * k4 + 0) * 64 + c];
        float w1 = Ws[(4 * k4 + 1) * 64 + c];
        float w2 = Ws[(4 * k4 + 2) * 64 + c];
        float w3 = Ws[(4 * k4 + 3) * 64 + c];
#pragma unroll
        for (int r = 0; r < 4; ++r) {
            acc[r] = fmaf(xv[r].x, w0, acc[r]);
            acc[r] = fmaf(xv[r].y, w1, acc[r]);
            acc[r] = fmaf(xv[r].z, w2, acc[r]);
            acc[r] = fmaf(xv[r].w, w3, acc[r]);
        }
    }

    float as_w = att_s[c];
    float ad_w = att_d[c];
#pragma unroll
    for (int r = 0; r < 4; ++r) {
        if (r >= nrows) break;
        int n = n0 + r;
        float a = acc[r];
        hout[(size_t)n * 64 + c] = __float2bfloat16(a);
        float vs = a * as_w;
        float vd = a * ad_w;
#pragma unroll
        for (int off = 1; off < C; off <<= 1) {
            vs += __shfl_xor(vs, off, 64);
            vd += __shfl_xor(vd, off, 64);
        }
        if ((c % C) == 0) {
            int hd = c / C;
            asrc[(size_t)n * H + hd] = vs;
            adst[(size_t)n * H + hd] = vd;
        }
    }
}

// ---- Edge-softmax aggregation (one wave per dst node, 16-wide chunks) ------

template <int H, int C, bool FINAL>
__global__ __launch_bounds__(256) void gat_edge_kernel(
    const bf16* __restrict__ h,      // [N,64] bf16
    const float* __restrict__ asrc,  // [N*H]
    const float* __restrict__ adst,  // [N*H]
    const int* __restrict__ row,     // [N+1]
    const int* __restrict__ esrc,    // [Etot]
    const float* __restrict__ bias,  // [64]
    float* __restrict__ out,         // [N,64]
    int N) {
    int tid  = threadIdx.x;
    int lane = tid & 63;
    int n    = blockIdx.x * 4 + (tid >> 6);
    if (n >= N) return;

    int hd = lane / C;
    float adn = adst[(size_t)n * H + hd];
    int e0 = row[n], e1 = row[n + 1];

    float m = -INFINITY, lsum = 0.f, acc = 0.f;
    for (int e = e0; e < e1; e += 16) {
        int s[16];
#pragma unroll
        for (int j = 0; j < 16; ++j) {
            int ee = e + j;
            s[j] = (ee < e1) ? esrc[ee] : 0;
        }
        bf16 hv16[16];
#pragma unroll
        for (int j = 0; j < 16; ++j) hv16[j] = h[(size_t)s[j] * 64 + lane];
        float al[16];
#pragma unroll
        for (int j = 0; j < 16; ++j) {
            float a = asrc[(size_t)s[j] * H + hd] + adn;
            a = a > 0.f ? a : 0.2f * a;                  // leaky_relu(0.2)
            al[j] = (e + j < e1) ? a : -INFINITY;
        }
        float cm = al[0];
#pragma unroll
        for (int j = 1; j < 16; ++j) cm = fmaxf(cm, al[j]);
        float mn    = fmaxf(m, cm);
        float scale = __expf(m - mn);                    // first chunk: exp(-inf)=0
        float ps = 0.f, pa = 0.f;
#pragma unroll
        for (int j = 0; j < 16; ++j) {
            float p = __expf(al[j] - mn);                // padded: exp(-inf)=0
            ps += p;
            pa = fmaf(p, __bfloat162float(hv16[j]), pa);
        }
        lsum = lsum * scale + ps;
        acc  = acc * scale + pa;
        m = mn;
    }

    float v = acc / (lsum + 1e-16f) + bias[lane];
    if (!FINAL) {
        out[(size_t)n * 64 + lane] = v > 0.f ? v : expm1f(v);   // ELU
    } else {
        float mx = v;
#pragma unroll
        for (int off = 1; off < 64; off <<= 1) mx = fmaxf(mx, __shfl_xor(mx, off, 64));
        float ex = __expf(v - mx);
        float sm = ex;
#pragma unroll
        for (int off = 1; off < 64; off <<= 1) sm += __shfl_xor(sm, off, 64);
        out[(size_t)n * 64 + lane] = (v - mx) - __logf(sm);
    }
}

// ---------------------------------------------------------------------------

extern "C" void kernel_launch(void* const* d_in, const int* in_sizes, int n_in,
                              void* d_out, int out_size, void* d_ws, size_t ws_size,
                              hipStream_t stream) {
    const float* x        = (const float*)d_in[0];   // [T,N,64]
    const int*   eidx     = (const int*)d_in[1];     // [2,E]
    const float* W1       = (const float*)d_in[2];
    const float* att_src1 = (const float*)d_in[3];
    const float* att_dst1 = (const float*)d_in[4];
    const float* bias1    = (const float*)d_in[5];
    const float* W2       = (const float*)d_in[6];
    const float* att_src2 = (const float*)d_in[7];
    const float* att_dst2 = (const float*)d_in[8];
    const float* bias2    = (const float*)d_in[9];
    float* dout = (float*)d_out;

    const int N = 50000;
    const int F = 64;
    const int E = in_sizes[1] / 2;
    const int T = in_sizes[0] / (N * F);
    const int Etot = E + N;

    const int* srcs = eidx;
    const int* dsts = eidx + E;

    char* ws = (char*)d_ws;
    size_t off = 0;
    auto carve = [&](size_t bytes) -> void* {
        void* p = ws + off;
        off = (off + bytes + 255) & ~(size_t)255;
        return p;
    };
    bf16*  h_buf = (bf16*)carve((size_t)N * 64 * sizeof(bf16));
    float* y1    = (float*)carve((size_t)N * 64 * sizeof(float));
    float* asrc  = (float*)carve((size_t)N * 8 * sizeof(float));
    float* adst  = (float*)carve((size_t)N * 8 * sizeof(float));
    int*   rowp  = (int*)carve((size_t)(N + 1) * sizeof(int));
    int*   cnt   = (int*)carve((size_t)N * sizeof(int));
    int*   cur   = (int*)carve((size_t)N * sizeof(int));
    int*   esrc  = (int*)carve((size_t)Etot * sizeof(int));
    (void)ws_size;

    init_cnt_kernel<<<(N + 255) / 256, 256, 0, stream>>>(cnt, N);
    count_edges_kernel<<<(E + 255) / 256, 256, 0, stream>>>(dsts, cnt, E);
    scan_kernel<<<1, 1024, 0, stream>>>(cnt, rowp, cur, N);
    fill_csr_kernel<<<(E + N + 255) / 256, 256, 0, stream>>>(srcs, dsts, cur, esrc, E, N);

    int gemm_grid = (N + 15) / 16;
    int edge_grid = (N + 3) / 4;
    for (int t = 0; t < T; ++t) {
        const float* xt = x + (size_t)t * N * F;
        float* ot = dout + (size_t)t * N * F;

        gemm_att_kernel<8, 8><<<gemm_grid, 256, 0, stream>>>(
            xt, W1, att_src1, att_dst1, h_buf, asrc, adst, N);
        gat_edge_kernel<8, 8, false><<<edge_grid, 256, 0, stream>>>(
            h_buf, asrc, adst, rowp, esrc, bias1, y1, N);
        gemm_att_kernel<1, 64><<<gemm_grid, 256, 0, stream>>>(
            y1, W2, att_src2, att_dst2, h_buf, asrc, adst, N);
        gat_edge_kernel<1, 64, true><<<edge_grid, 256, 0, stream>>>(
            h_buf, asrc, adst, rowp, esrc, bias2, ot, N);
    }
}

// Round 7
// 1609.825 us; speedup vs baseline: 2.3749x; 1.4586x over previous
//
#include <hip/hip_runtime.h>
#include <hip/hip_bf16.h>
#include <math.h>

// ---------------------------------------------------------------------------
// GAT 2-layer network on MI355X.
// CSR (by dst) built once; then 4 BATCHED stage kernels over all T=8
// timesteps (gemm1+att, edge1+ELU, gemm2+att, edge2+log_softmax) -> only 8
// dispatches total (was 68; inter-dispatch gaps + tails dominated).
// Edge agg: one wave per (t,node), flash-style online softmax, 8-wide edge
// chunks. Feature tables h and y1 in bf16 (halves gather bytes; f32
// accumulation everywhere).
// ---------------------------------------------------------------------------

typedef __hip_bfloat16 bf16;

__device__ __forceinline__ float bf2f(unsigned short u) {
    return __uint_as_float(((unsigned int)u) << 16);
}

// ---- CSR construction ------------------------------------------------------

__global__ __launch_bounds__(256) void init_cnt_kernel(int* cnt, int N) {
    int i = blockIdx.x * 256 + threadIdx.x;
    if (i < N) cnt[i] = 1;  // self-loop contributes 1 to every node
}

__global__ __launch_bounds__(256) void count_edges_kernel(const int* __restrict__ dsts,
                                                          int* cnt, int E) {
    int i = blockIdx.x * 256 + threadIdx.x;
    if (i < E) atomicAdd(&cnt[dsts[i]], 1);
}

__global__ __launch_bounds__(1024) void scan_kernel(const int* __restrict__ cnt,
                                                    int* row, int* cur, int N) {
    __shared__ int ls[1024];
    int t = threadIdx.x;
    int chunk = (N + 1023) / 1024;
    int b = t * chunk;
    int sum = 0;
    for (int i = 0; i < chunk; ++i) {
        int idx = b + i;
        if (idx < N) sum += cnt[idx];
    }
    ls[t] = sum;
    __syncthreads();
    for (int off = 1; off < 1024; off <<= 1) {
        int v = (t >= off) ? ls[t - off] : 0;
        __syncthreads();
        ls[t] += v;
        __syncthreads();
    }
    int run = (t == 0) ? 0 : ls[t - 1];
    for (int i = 0; i < chunk; ++i) {
        int idx = b + i;
        if (idx < N) {
            int c = cnt[idx];
            row[idx] = run;
            cur[idx] = run;
            run += c;
        }
    }
    if (t == 1023) row[N] = ls[1023];
}

__global__ __launch_bounds__(256) void fill_csr_kernel(const int* __restrict__ srcs,
                                                       const int* __restrict__ dsts,
                                                       int* cur, int* esrc, int E, int N) {
    int i = blockIdx.x * 256 + threadIdx.x;
    if (i >= E + N) return;
    int s, d;
    if (i < E) { s = srcs[i]; d = dsts[i]; }
    else       { s = i - E;   d = s; }      // self-loops appended
    int pos = atomicAdd(&cur[d], 1);
    esrc[pos] = s;
}

// ---- vector loaders --------------------------------------------------------

__device__ __forceinline__ float4 ld4(const float* p) { return *(const float4*)p; }
__device__ __forceinline__ float4 ld4(const bf16* p) {
    ushort4 u = *(const ushort4*)p;
    float4 r;
    r.x = bf2f(u.x); r.y = bf2f(u.y); r.z = bf2f(u.z); r.w = bf2f(u.w);
    return r;
}

// ---- GEMM (h = x@W) fused with attention dot-products, batched over rows ---
// W in LDS (16KB). 4 rows per wave, lane c = output column. h stored bf16;
// a_src/a_dst computed from the unrounded f32 accumulator. R = T*N rows.

template <typename TIN, int H, int C>
__global__ __launch_bounds__(256) void gemm_att_kernel(
    const TIN* __restrict__ xin,     // [R,64]
    const float* __restrict__ Wm,    // [64,64]  h[r,c] = sum_k x[r,k]*W[k,c]
    const float* __restrict__ att_s, // [H*C]
    const float* __restrict__ att_d, // [H*C]
    bf16* __restrict__ hout,         // [R,64] bf16
    float* __restrict__ asrc,        // [R*H]
    float* __restrict__ adst,        // [R*H]
    int R) {
    __shared__ float Ws[64 * 64];
    int tid = threadIdx.x;
    {
        const float4* W4 = (const float4*)Wm;
        float4* Ws4 = (float4*)Ws;
#pragma unroll
        for (int i = 0; i < 4; ++i) Ws4[tid + 256 * i] = W4[tid + 256 * i];
    }
    __syncthreads();

    int c  = tid & 63;
    int wv = tid >> 6;
    int n0 = (blockIdx.x * 4 + wv) * 4;
    if (n0 >= R) return;
    int nrows = (R - n0 >= 4) ? 4 : (R - n0);

    const TIN* xb = xin + (size_t)n0 * 64;
    float acc[4] = {0.f, 0.f, 0.f, 0.f};

#pragma unroll 2
    for (int k4 = 0; k4 < 16; ++k4) {
        float4 xv[4];
#pragma unroll
        for (int r = 0; r < 4; ++r) {
            int rr = (r < nrows) ? r : 0;
            xv[r] = ld4(xb + (size_t)rr * 64 + k4 * 4);
        }
        float w0 = Ws[(4 * k4 + 0) * 64 + c];
        float w1 = Ws[(4 * k4 + 1) * 64 + c];
        float w2 = Ws[(4 * k4 + 2) * 64 + c];
        float w3 = Ws[(4 * k4 + 3) * 64 + c];
#pragma unroll
        for (int r = 0; r < 4; ++r) {
            acc[r] = fmaf(xv[r].x, w0, acc[r]);
            acc[r] = fmaf(xv[r].y, w1, acc[r]);
            acc[r] = fmaf(xv[r].z, w2, acc[r]);
            acc[r] = fmaf(xv[r].w, w3, acc[r]);
        }
    }

    float as_w = att_s[c];
    float ad_w = att_d[c];
#pragma unroll
    for (int r = 0; r < 4; ++r) {
        if (r >= nrows) break;
        int n = n0 + r;
        float a = acc[r];
        hout[(size_t)n * 64 + c] = __float2bfloat16(a);
        float vs = a * as_w;
        float vd = a * ad_w;
#pragma unroll
        for (int off = 1; off < C; off <<= 1) {
            vs += __shfl_xor(vs, off, 64);
            vd += __shfl_xor(vd, off, 64);
        }
        if ((c % C) == 0) {
            int hd = c / C;
            asrc[(size_t)n * H + hd] = vs;
            adst[(size_t)n * H + hd] = vd;
        }
    }
}

// ---- Edge-softmax aggregation, batched over timesteps ----------------------
// One wave per (t, dst node); grid is t-major (BPT blocks per timestep) so
// concurrently-resident blocks share one timestep's h table (L2 locality).

template <int H, int C, bool FINAL>
__global__ __launch_bounds__(256) void gat_edge_kernel(
    const bf16* __restrict__ h_all,     // [T*N,64] bf16
    const float* __restrict__ asrc_all, // [T*N*H]
    const float* __restrict__ adst_all, // [T*N*H]
    const int* __restrict__ row,        // [N+1]
    const int* __restrict__ esrc,       // [Etot]
    const float* __restrict__ bias,     // [64]
    bf16* __restrict__ outb,            // [T*N,64] bf16   (used if !FINAL)
    float* __restrict__ outf,           // [T*N,64] f32    (used if FINAL)
    int N, int BPT, int Etot) {
    int tid  = threadIdx.x;
    int lane = tid & 63;
    int t  = blockIdx.x / BPT;
    int nb = blockIdx.x - t * BPT;
    int n  = nb * 4 + (tid >> 6);
    if (n >= N) return;

    const bf16*  h    = h_all    + (size_t)t * N * 64;
    const float* asrc = asrc_all + (size_t)t * N * H;
    const float* adst = adst_all + (size_t)t * N * H;

    int hd = lane / C;
    float adn = adst[(size_t)n * H + hd];
    int e0 = row[n], e1 = row[n + 1];
    // defensive clamps (cost-free; protect against any stale/poisoned ws)
    if (e0 < 0) e0 = 0;
    if (e1 > Etot) e1 = Etot;

    float m = -INFINITY, lsum = 0.f, acc = 0.f;
    for (int e = e0; e < e1; e += 8) {
        int s[8];
#pragma unroll
        for (int j = 0; j < 8; ++j) {
            int ee = e + j;
            int sv = (ee < e1) ? esrc[ee] : 0;
            s[j] = ((unsigned)sv < (unsigned)N) ? sv : 0;   // clamp OOB
        }
        unsigned short hv16[8];
#pragma unroll
        for (int j = 0; j < 8; ++j)
            hv16[j] = *(const unsigned short*)(h + (size_t)s[j] * 64 + lane);
        float al[8];
#pragma unroll
        for (int j = 0; j < 8; ++j) {
            float a = asrc[(size_t)s[j] * H + hd] + adn;
            a = a > 0.f ? a : 0.2f * a;                  // leaky_relu(0.2)
            al[j] = (e + j < e1) ? a : -INFINITY;
        }
        float cm = al[0];
#pragma unroll
        for (int j = 1; j < 8; ++j) cm = fmaxf(cm, al[j]);
        float mn    = fmaxf(m, cm);
        float scale = __expf(m - mn);                    // first chunk: exp(-inf)=0
        float ps = 0.f, pa = 0.f;
#pragma unroll
        for (int j = 0; j < 8; ++j) {
            float p = __expf(al[j] - mn);                // padded: exp(-inf)=0
            ps += p;
            pa = fmaf(p, bf2f(hv16[j]), pa);
        }
        lsum = lsum * scale + ps;
        acc  = acc * scale + pa;
        m = mn;
    }

    float v = acc / (lsum + 1e-16f) + bias[lane];
    size_t oidx = ((size_t)t * N + n) * 64 + lane;
    if (!FINAL) {
        float y = v > 0.f ? v : expm1f(v);               // ELU
        outb[oidx] = __float2bfloat16(y);
    } else {
        float mx = v;
#pragma unroll
        for (int off = 1; off < 64; off <<= 1) mx = fmaxf(mx, __shfl_xor(mx, off, 64));
        float ex = __expf(v - mx);
        float sm = ex;
#pragma unroll
        for (int off = 1; off < 64; off <<= 1) sm += __shfl_xor(sm, off, 64);
        outf[oidx] = (v - mx) - __logf(sm);
    }
}

// ---------------------------------------------------------------------------

extern "C" void kernel_launch(void* const* d_in, const int* in_sizes, int n_in,
                              void* d_out, int out_size, void* d_ws, size_t ws_size,
                              hipStream_t stream) {
    const float* x        = (const float*)d_in[0];   // [T,N,64]
    const int*   eidx     = (const int*)d_in[1];     // [2,E]
    const float* W1       = (const float*)d_in[2];
    const float* att_src1 = (const float*)d_in[3];
    const float* att_dst1 = (const float*)d_in[4];
    const float* bias1    = (const float*)d_in[5];
    const float* W2       = (const float*)d_in[6];
    const float* att_src2 = (const float*)d_in[7];
    const float* att_dst2 = (const float*)d_in[8];
    const float* bias2    = (const float*)d_in[9];
    float* dout = (float*)d_out;

    const int N = 50000;
    const int F = 64;
    const int E = in_sizes[1] / 2;
    const int T = in_sizes[0] / (N * F);
    const int NT = T * N;
    const int Etot = E + N;
    const int BPT = (N + 3) / 4;          // blocks per timestep (4 nodes/block)

    const int* srcs = eidx;
    const int* dsts = eidx + E;

    char* ws = (char*)d_ws;
    size_t off = 0;
    auto carve = [&](size_t bytes) -> void* {
        void* p = ws + off;
        off = (off + bytes + 255) & ~(size_t)255;
        return p;
    };
    // batched layout (bf16 h & y1): ~135 MB
    bf16*  h_all  = (bf16*)carve((size_t)NT * 64 * sizeof(bf16));
    bf16*  y1_all = (bf16*)carve((size_t)NT * 64 * sizeof(bf16));
    float* asrc   = (float*)carve((size_t)NT * 8 * sizeof(float));
    float* adst   = (float*)carve((size_t)NT * 8 * sizeof(float));
    int*   rowp   = (int*)carve((size_t)(N + 1) * sizeof(int));
    int*   cnt    = (int*)carve((size_t)N * sizeof(int));
    int*   cur    = (int*)carve((size_t)N * sizeof(int));
    int*   esrc   = (int*)carve((size_t)Etot * sizeof(int));
    bool batched = (off <= ws_size);

    if (batched) {
        // --- CSR (graph identical across timesteps) ---
        init_cnt_kernel<<<(N + 255) / 256, 256, 0, stream>>>(cnt, N);
        count_edges_kernel<<<(E + 255) / 256, 256, 0, stream>>>(dsts, cnt, E);
        scan_kernel<<<1, 1024, 0, stream>>>(cnt, rowp, cur, N);
        fill_csr_kernel<<<(E + N + 255) / 256, 256, 0, stream>>>(srcs, dsts, cur, esrc, E, N);

        int gemm_grid = (NT + 15) / 16;
        int edge_grid = BPT * T;
        gemm_att_kernel<float, 8, 8><<<gemm_grid, 256, 0, stream>>>(
            x, W1, att_src1, att_dst1, h_all, asrc, adst, NT);
        gat_edge_kernel<8, 8, false><<<edge_grid, 256, 0, stream>>>(
            h_all, asrc, adst, rowp, esrc, bias1, y1_all, nullptr, N, BPT, Etot);
        gemm_att_kernel<bf16, 1, 64><<<gemm_grid, 256, 0, stream>>>(
            y1_all, W2, att_src2, att_dst2, h_all, asrc, adst, NT);
        gat_edge_kernel<1, 64, true><<<edge_grid, 256, 0, stream>>>(
            h_all, asrc, adst, rowp, esrc, bias2, nullptr, dout, N, BPT, Etot);
    } else {
        // fallback: per-timestep with small buffers (re-carve)
        off = 0;
        bf16*  h1  = (bf16*)carve((size_t)N * 64 * sizeof(bf16));
        bf16*  y1  = (bf16*)carve((size_t)N * 64 * sizeof(bf16));
        float* as1 = (float*)carve((size_t)N * 8 * sizeof(float));
        float* ad1 = (float*)carve((size_t)N * 8 * sizeof(float));
        int*   rp  = (int*)carve((size_t)(N + 1) * sizeof(int));
        int*   cn  = (int*)carve((size_t)N * sizeof(int));
        int*   cu  = (int*)carve((size_t)N * sizeof(int));
        int*   es  = (int*)carve((size_t)Etot * sizeof(int));
        init_cnt_kernel<<<(N + 255) / 256, 256, 0, stream>>>(cn, N);
        count_edges_kernel<<<(E + 255) / 256, 256, 0, stream>>>(dsts, cn, E);
        scan_kernel<<<1, 1024, 0, stream>>>(cn, rp, cu, N);
        fill_csr_kernel<<<(E + N + 255) / 256, 256, 0, stream>>>(srcs, dsts, cu, es, E, N);
        int gemm_grid = (N + 15) / 16;
        for (int t = 0; t < T; ++t) {
            const float* xt = x + (size_t)t * N * F;
            float* ot = dout + (size_t)t * N * F;
            gemm_att_kernel<float, 8, 8><<<gemm_grid, 256, 0, stream>>>(
                xt, W1, att_src1, att_dst1, h1, as1, ad1, N);
            gat_edge_kernel<8, 8, false><<<BPT, 256, 0, stream>>>(
                h1, as1, ad1, rp, es, bias1, y1, nullptr, N, BPT, Etot);
            gemm_att_kernel<bf16, 1, 64><<<gemm_grid, 256, 0, stream>>>(
                y1, W2, att_src2, att_dst2, h1, as1, ad1, N);
            gat_edge_kernel<1, 64, true><<<BPT, 256, 0, stream>>>(
                h1, as1, ad1, rp, es, bias2, nullptr, ot, N, BPT, Etot);
        }
    }
}

// Round 9
// 1473.569 us; speedup vs baseline: 2.5945x; 1.0925x over previous
//
#include <hip/hip_runtime.h>
#include <hip/hip_bf16.h>
#include <math.h>

// ---------------------------------------------------------------------------
// GAT 2-layer network on MI355X.
// CSR (by dst) built once; 4 batched stage kernels over all T=8 timesteps.
// Edge agg (VALU-bound per r7 counters): edge-parallel alpha/exp
//   - lane-parallel esrc preload (one coalesced load per node, shfl bcast)
//   - alpha+exp computed once per (edge,head) across lanes, not per channel
//   - 32-bit gather offsets
// h / y1 tables bf16; f32 accumulation everywhere.
// ---------------------------------------------------------------------------

typedef __hip_bfloat16 bf16;

__device__ __forceinline__ float bf2f(unsigned short u) {
    return __uint_as_float(((unsigned int)u) << 16);
}

// ---- CSR construction ------------------------------------------------------

__global__ __launch_bounds__(256) void init_cnt_kernel(int* cnt, int N) {
    int i = blockIdx.x * 256 + threadIdx.x;
    if (i < N) cnt[i] = 1;  // self-loop contributes 1 to every node
}

__global__ __launch_bounds__(256) void count_edges_kernel(const int* __restrict__ dsts,
                                                          int* cnt, int E) {
    int i = blockIdx.x * 256 + threadIdx.x;
    if (i < E) atomicAdd(&cnt[dsts[i]], 1);
}

__global__ __launch_bounds__(1024) void scan_kernel(const int* __restrict__ cnt,
                                                    int* row, int* cur, int N) {
    __shared__ int ls[1024];
    int t = threadIdx.x;
    int chunk = (N + 1023) / 1024;
    int b = t * chunk;
    int sum = 0;
    for (int i = 0; i < chunk; ++i) {
        int idx = b + i;
        if (idx < N) sum += cnt[idx];
    }
    ls[t] = sum;
    __syncthreads();
    for (int off = 1; off < 1024; off <<= 1) {
        int v = (t >= off) ? ls[t - off] : 0;
        __syncthreads();
        ls[t] += v;
        __syncthreads();
    }
    int run = (t == 0) ? 0 : ls[t - 1];
    for (int i = 0; i < chunk; ++i) {
        int idx = b + i;
        if (idx < N) {
            int c = cnt[idx];
            row[idx] = run;
            cur[idx] = run;
            run += c;
        }
    }
    if (t == 1023) row[N] = ls[1023];
}

__global__ __launch_bounds__(256) void fill_csr_kernel(const int* __restrict__ srcs,
                                                       const int* __restrict__ dsts,
                                                       int* cur, int* esrc, int E, int N) {
    int i = blockIdx.x * 256 + threadIdx.x;
    if (i >= E + N) return;
    int s, d;
    if (i < E) { s = srcs[i]; d = dsts[i]; }
    else       { s = i - E;   d = s; }      // self-loops appended
    int pos = atomicAdd(&cur[d], 1);
    esrc[pos] = s;
}

// ---- vector loaders --------------------------------------------------------

__device__ __forceinline__ float4 ld4(const float* p) { return *(const float4*)p; }
__device__ __forceinline__ float4 ld4(const bf16* p) {
    ushort4 u = *(const ushort4*)p;
    float4 r;
    r.x = bf2f(u.x); r.y = bf2f(u.y); r.z = bf2f(u.z); r.w = bf2f(u.w);
    return r;
}

// ---- GEMM (h = x@W) fused with attention dot-products, batched over rows ---

template <typename TIN, int H, int C>
__global__ __launch_bounds__(256) void gemm_att_kernel(
    const TIN* __restrict__ xin,     // [R,64]
    const float* __restrict__ Wm,    // [64,64]
    const float* __restrict__ att_s, // [H*C]
    const float* __restrict__ att_d, // [H*C]
    bf16* __restrict__ hout,         // [R,64] bf16
    float* __restrict__ asrc,        // [R*H]
    float* __restrict__ adst,        // [R*H]
    int R) {
    __shared__ float Ws[64 * 64];
    int tid = threadIdx.x;
    {
        const float4* W4 = (const float4*)Wm;
        float4* Ws4 = (float4*)Ws;
#pragma unroll
        for (int i = 0; i < 4; ++i) Ws4[tid + 256 * i] = W4[tid + 256 * i];
    }
    __syncthreads();

    int c  = tid & 63;
    int wv = tid >> 6;
    int n0 = (blockIdx.x * 4 + wv) * 4;
    if (n0 >= R) return;
    int nrows = (R - n0 >= 4) ? 4 : (R - n0);

    const TIN* xb = xin + (size_t)n0 * 64;
    float acc[4] = {0.f, 0.f, 0.f, 0.f};

#pragma unroll 2
    for (int k4 = 0; k4 < 16; ++k4) {
        float4 xv[4];
#pragma unroll
        for (int r = 0; r < 4; ++r) {
            int rr = (r < nrows) ? r : 0;
            xv[r] = ld4(xb + (size_t)rr * 64 + k4 * 4);
        }
        float w0 = Ws[(4 * k4 + 0) * 64 + c];
        float w1 = Ws[(4 * k4 + 1) * 64 + c];
        float w2 = Ws[(4 * k4 + 2) * 64 + c];
        float w3 = Ws[(4 * k4 + 3) * 64 + c];
#pragma unroll
        for (int r = 0; r < 4; ++r) {
            acc[r] = fmaf(xv[r].x, w0, acc[r]);
            acc[r] = fmaf(xv[r].y, w1, acc[r]);
            acc[r] = fmaf(xv[r].z, w2, acc[r]);
            acc[r] = fmaf(xv[r].w, w3, acc[r]);
        }
    }

    float as_w = att_s[c];
    float ad_w = att_d[c];
#pragma unroll
    for (int r = 0; r < 4; ++r) {
        if (r >= nrows) break;
        int n = n0 + r;
        float a = acc[r];
        hout[(size_t)n * 64 + c] = __float2bfloat16(a);
        float vs = a * as_w;
        float vd = a * ad_w;
#pragma unroll
        for (int off = 1; off < C; off <<= 1) {
            vs += __shfl_xor(vs, off, 64);
            vd += __shfl_xor(vd, off, 64);
        }
        if ((c % C) == 0) {
            int hd = c / C;
            asrc[(size_t)n * H + hd] = vs;
            adst[(size_t)n * H + hd] = vd;
        }
    }
}

// ---- Edge-softmax aggregation, edge-parallel alpha -------------------------
// One wave per (t, dst node). Lane roles:
//   alpha phase: lane l -> (edge jl = l>>LH, head l&(H-1))
//   accum phase: lane c -> channel c, head c>>(6-LH)
// Up to 64 src indices preloaded coalesced into lane registers per block.

template <int H, bool FINAL>
__global__ __launch_bounds__(256) void gat_edge_kernel(
    const bf16* __restrict__ h_all,     // [T*N,64] bf16
    const float* __restrict__ asrc_all, // [T*N*H]
    const float* __restrict__ adst_all, // [T*N*H]
    const int* __restrict__ row,        // [N+1]
    const int* __restrict__ esrc,       // [Etot]
    const float* __restrict__ bias,     // [64]
    bf16* __restrict__ outb,            // (!FINAL) [T*N,64] bf16
    float* __restrict__ outf,           // (FINAL)  [T*N,64] f32
    int N, int BPT) {
    constexpr int LH   = (H == 8) ? 3 : 0;  // log2(H)
    constexpr int SUB  = 64 >> LH;          // edges per sub-chunk
    constexpr int NSUB = 1 << LH;           // sub-chunks per 64-edge preload

    int tid  = threadIdx.x;
    int lane = tid & 63;
    int t  = blockIdx.x / BPT;
    int nb = blockIdx.x - t * BPT;
    int n  = nb * 4 + (tid >> 6);
    if (n >= N) return;

    const bf16*  h    = h_all    + (size_t)t * N * 64;
    const float* asrc = asrc_all + (size_t)t * N * H;
    const float* adst = adst_all + (size_t)t * N * H;

    const int head_a = lane & (H - 1);       // alpha-layout head
    const int hd_acc = lane >> (6 - LH);     // accum-layout head
    float adn_a = adst[(unsigned)n * H + head_a];

    int e0  = row[n];
    int deg = row[n + 1] - e0;

    float m_al = -INFINITY, m_ac = -INFINITY;
    float lsum_lane = 0.f;
    float acc = 0.f;

    for (int base = 0; base < deg; base += 64) {
        int cnt = deg - base; if (cnt > 64) cnt = 64;
        int sv = (lane < cnt) ? esrc[e0 + base + lane] : 0;

#pragma unroll
        for (int sub = 0; sub < NSUB; ++sub) {
            const int jbase = sub * SUB;
            if (jbase >= cnt) break;
            // ---- alpha phase (edge-parallel) ----
            int jl = lane >> LH;
            int je = jbase + jl;
            int svj = (H == 1) ? sv : __shfl(sv, je, 64);
            float av = asrc[((unsigned)svj << LH) + head_a];
            float a = av + adn_a;
            a = a > 0.f ? a : 0.2f * a;                  // leaky_relu(0.2)
            a = (je < cnt) ? a : -INFINITY;
            float cm = a;
#pragma unroll
            for (int o = H; o < 64; o <<= 1) cm = fmaxf(cm, __shfl_xor(cm, o, 64));
            float mn_al = fmaxf(m_al, cm);
            float sc_al = __expf(m_al - mn_al);          // first chunk: exp(-inf)=0
            m_al = mn_al;
            float p = __expf(a - mn_al);                 // invalid: exp(-inf)=0
            lsum_lane = lsum_lane * sc_al + p;
            // ---- rescale accumulator (accum layout) ----
            float cm_ac = (H == 1) ? cm : __shfl(cm, hd_acc, 64);
            float mn_ac = fmaxf(m_ac, cm_ac);
            float sc_ac = __expf(m_ac - mn_ac);
            m_ac = mn_ac;
            acc *= sc_ac;
            // ---- accumulate edges (lane = channel), blocks of 8 ----
            int jend = cnt - jbase; if (jend > SUB) jend = SUB;
            for (int j0 = 0; j0 < jend; j0 += 8) {
#pragma unroll
                for (int q = 0; q < 8; ++q) {
                    int j = j0 + q;                      // may exceed jend: p==0 there
                    float pj = __shfl(p, (j << LH) | hd_acc, 64);
                    int sj = __shfl(sv, jbase + j, 64);
                    float hvf = bf2f(*(const unsigned short*)(h + (((unsigned)sj << 6) | lane)));
                    acc = fmaf(pj, hvf, acc);
                }
            }
        }
    }

    // lsum: reduce partials over edge-slots within each head group
    float ls = lsum_lane;
#pragma unroll
    for (int o = H; o < 64; o <<= 1) ls += __shfl_xor(ls, o, 64);
    float lsum = (H == 1) ? ls : __shfl(ls, hd_acc, 64);

    float v = acc / (lsum + 1e-16f) + bias[lane];
    size_t oidx = ((size_t)t * N + n) * 64 + lane;
    if (!FINAL) {
        float y = v > 0.f ? v : expm1f(v);               // ELU
        outb[oidx] = __float2bfloat16(y);
    } else {
        float mx = v;
#pragma unroll
        for (int off = 1; off < 64; off <<= 1) mx = fmaxf(mx, __shfl_xor(mx, off, 64));
        float ex = __expf(v - mx);
        float sm = ex;
#pragma unroll
        for (int off = 1; off < 64; off <<= 1) sm += __shfl_xor(sm, off, 64);
        outf[oidx] = (v - mx) - __logf(sm);
    }
}

// ---------------------------------------------------------------------------

extern "C" void kernel_launch(void* const* d_in, const int* in_sizes, int n_in,
                              void* d_out, int out_size, void* d_ws, size_t ws_size,
                              hipStream_t stream) {
    const float* x        = (const float*)d_in[0];   // [T,N,64]
    const int*   eidx     = (const int*)d_in[1];     // [2,E]
    const float* W1       = (const float*)d_in[2];
    const float* att_src1 = (const float*)d_in[3];
    const float* att_dst1 = (const float*)d_in[4];
    const float* bias1    = (const float*)d_in[5];
    const float* W2       = (const float*)d_in[6];
    const float* att_src2 = (const float*)d_in[7];
    const float* att_dst2 = (const float*)d_in[8];
    const float* bias2    = (const float*)d_in[9];
    float* dout = (float*)d_out;

    const int N = 50000;
    const int F = 64;
    const int E = in_sizes[1] / 2;
    const int T = in_sizes[0] / (N * F);
    const int NT = T * N;
    const int Etot = E + N;
    const int BPT = (N + 3) / 4;          // blocks per timestep (4 nodes/block)

    const int* srcs = eidx;
    const int* dsts = eidx + E;

    char* ws = (char*)d_ws;
    size_t off = 0;
    auto carve = [&](size_t bytes) -> void* {
        void* p = ws + off;
        off = (off + bytes + 255) & ~(size_t)255;
        return p;
    };
    bf16*  h_all  = (bf16*)carve((size_t)NT * 64 * sizeof(bf16));
    bf16*  y1_all = (bf16*)carve((size_t)NT * 64 * sizeof(bf16));
    float* asrc   = (float*)carve((size_t)NT * 8 * sizeof(float));
    float* adst   = (float*)carve((size_t)NT * 8 * sizeof(float));
    int*   rowp   = (int*)carve((size_t)(N + 1) * sizeof(int));
    int*   cnt    = (int*)carve((size_t)N * sizeof(int));
    int*   cur    = (int*)carve((size_t)N * sizeof(int));
    int*   esrc   = (int*)carve((size_t)Etot * sizeof(int));
    bool batched = (off <= ws_size);

    if (batched) {
        init_cnt_kernel<<<(N + 255) / 256, 256, 0, stream>>>(cnt, N);
        count_edges_kernel<<<(E + 255) / 256, 256, 0, stream>>>(dsts, cnt, E);
        scan_kernel<<<1, 1024, 0, stream>>>(cnt, rowp, cur, N);
        fill_csr_kernel<<<(E + N + 255) / 256, 256, 0, stream>>>(srcs, dsts, cur, esrc, E, N);

        int gemm_grid = (NT + 15) / 16;
        int edge_grid = BPT * T;
        gemm_att_kernel<float, 8, 8><<<gemm_grid, 256, 0, stream>>>(
            x, W1, att_src1, att_dst1, h_all, asrc, adst, NT);
        gat_edge_kernel<8, false><<<edge_grid, 256, 0, stream>>>(
            h_all, asrc, adst, rowp, esrc, bias1, y1_all, nullptr, N, BPT);
        gemm_att_kernel<bf16, 1, 64><<<gemm_grid, 256, 0, stream>>>(
            y1_all, W2, att_src2, att_dst2, h_all, asrc, adst, NT);
        gat_edge_kernel<1, true><<<edge_grid, 256, 0, stream>>>(
            h_all, asrc, adst, rowp, esrc, bias2, nullptr, dout, N, BPT);
    } else {
        // fallback: per-timestep with small buffers (re-carve)
        off = 0;
        bf16*  h1  = (bf16*)carve((size_t)N * 64 * sizeof(bf16));
        bf16*  y1  = (bf16*)carve((size_t)N * 64 * sizeof(bf16));
        float* as1 = (float*)carve((size_t)N * 8 * sizeof(float));
        float* ad1 = (float*)carve((size_t)N * 8 * sizeof(float));
        int*   rp  = (int*)carve((size_t)(N + 1) * sizeof(int));
        int*   cn  = (int*)carve((size_t)N * sizeof(int));
        int*   cu  = (int*)carve((size_t)N * sizeof(int));
        int*   es  = (int*)carve((size_t)Etot * sizeof(int));
        init_cnt_kernel<<<(N + 255) / 256, 256, 0, stream>>>(cn, N);
        count_edges_kernel<<<(E + 255) / 256, 256, 0, stream>>>(dsts, cn, E);
        scan_kernel<<<1, 1024, 0, stream>>>(cn, rp, cu, N);
        fill_csr_kernel<<<(E + N + 255) / 256, 256, 0, stream>>>(srcs, dsts, cu, es, E, N);
        int gemm_grid = (N + 15) / 16;
        for (int t = 0; t < T; ++t) {
            const float* xt = x + (size_t)t * N * F;
            float* ot = dout + (size_t)t * N * F;
            gemm_att_kernel<float, 8, 8><<<gemm_grid, 256, 0, stream>>>(
                xt, W1, att_src1, att_dst1, h1, as1, ad1, N);
            gat_edge_kernel<8, false><<<(N + 3) / 4, 256, 0, stream>>>(
                h1, as1, ad1, rp, es, bias1, y1, nullptr, N, (N + 3) / 4);
            gemm_att_kernel<bf16, 1, 64><<<gemm_grid, 256, 0, stream>>>(
                y1, W2, att_src2, att_dst2, h1, as1, ad1, N);
            gat_edge_kernel<1, true><<<(N + 3) / 4, 256, 0, stream>>>(
                h1, as1, ad1, rp, es, bias2, nullptr, ot, N, (N + 3) / 4);
        }
    }
}

// Round 11
// 1294.990 us; speedup vs baseline: 2.9523x; 1.1379x over previous
//
#include <hip/hip_runtime.h>
#include <hip/hip_bf16.h>
#include <math.h>

// ---------------------------------------------------------------------------
// GAT 2-layer network on MI355X.
// CSR (by dst) built once; 4 batched stage kernels over all T=8 timesteps.
// Edge agg: edge-parallel alpha with ONE max ceremony per 64-edge chunk;
// accumulate phase uses SGPR src-index (readlane) -> scalar-base gathers,
// static ds_swizzle p-broadcast (H=8, macro-literal offsets) / SGPR p (H=1).
// h / y1 tables bf16; f32 accumulation everywhere.
// ---------------------------------------------------------------------------

typedef __hip_bfloat16 bf16;

__device__ __forceinline__ float bf2f(unsigned short u) {
    return __uint_as_float(((unsigned int)u) << 16);
}

// ---- CSR construction ------------------------------------------------------

__global__ __launch_bounds__(256) void init_cnt_kernel(int* cnt, int N) {
    int i = blockIdx.x * 256 + threadIdx.x;
    if (i < N) cnt[i] = 1;  // self-loop contributes 1 to every node
}

__global__ __launch_bounds__(256) void count_edges_kernel(const int* __restrict__ dsts,
                                                          int* cnt, int E) {
    int i = blockIdx.x * 256 + threadIdx.x;
    if (i < E) atomicAdd(&cnt[dsts[i]], 1);
}

__global__ __launch_bounds__(1024) void scan_kernel(const int* __restrict__ cnt,
                                                    int* row, int* cur, int N) {
    __shared__ int ls[1024];
    int t = threadIdx.x;
    int chunk = (N + 1023) / 1024;
    int b = t * chunk;
    int sum = 0;
    for (int i = 0; i < chunk; ++i) {
        int idx = b + i;
        if (idx < N) sum += cnt[idx];
    }
    ls[t] = sum;
    __syncthreads();
    for (int off = 1; off < 1024; off <<= 1) {
        int v = (t >= off) ? ls[t - off] : 0;
        __syncthreads();
        ls[t] += v;
        __syncthreads();
    }
    int run = (t == 0) ? 0 : ls[t - 1];
    for (int i = 0; i < chunk; ++i) {
        int idx = b + i;
        if (idx < N) {
            int c = cnt[idx];
            row[idx] = run;
            cur[idx] = run;
            run += c;
        }
    }
    if (t == 1023) row[N] = ls[1023];
}

__global__ __launch_bounds__(256) void fill_csr_kernel(const int* __restrict__ srcs,
                                                       const int* __restrict__ dsts,
                                                       int* cur, int* esrc, int E, int N) {
    int i = blockIdx.x * 256 + threadIdx.x;
    if (i >= E + N) return;
    int s, d;
    if (i < E) { s = srcs[i]; d = dsts[i]; }
    else       { s = i - E;   d = s; }      // self-loops appended
    int pos = atomicAdd(&cur[d], 1);
    esrc[pos] = s;
}

// ---- vector loaders --------------------------------------------------------

__device__ __forceinline__ float4 ld4(const float* p) { return *(const float4*)p; }
__device__ __forceinline__ float4 ld4(const bf16* p) {
    ushort4 u = *(const ushort4*)p;
    float4 r;
    r.x = bf2f(u.x); r.y = bf2f(u.y); r.z = bf2f(u.z); r.w = bf2f(u.w);
    return r;
}

// ---- GEMM (h = x@W) fused with attention dot-products, batched over rows ---

template <typename TIN, int H, int C>
__global__ __launch_bounds__(256) void gemm_att_kernel(
    const TIN* __restrict__ xin,     // [R,64]
    const float* __restrict__ Wm,    // [64,64]
    const float* __restrict__ att_s, // [H*C]
    const float* __restrict__ att_d, // [H*C]
    bf16* __restrict__ hout,         // [R,64] bf16
    float* __restrict__ asrc,        // [R*H]
    float* __restrict__ adst,        // [R*H]
    int R) {
    __shared__ float Ws[64 * 64];
    int tid = threadIdx.x;
    {
        const float4* W4 = (const float4*)Wm;
        float4* Ws4 = (float4*)Ws;
#pragma unroll
        for (int i = 0; i < 4; ++i) Ws4[tid + 256 * i] = W4[tid + 256 * i];
    }
    __syncthreads();

    int c  = tid & 63;
    int wv = tid >> 6;
    int n0 = (blockIdx.x * 4 + wv) * 4;
    if (n0 >= R) return;
    int nrows = (R - n0 >= 4) ? 4 : (R - n0);

    const TIN* xb = xin + (size_t)n0 * 64;
    float acc[4] = {0.f, 0.f, 0.f, 0.f};

#pragma unroll 2
    for (int k4 = 0; k4 < 16; ++k4) {
        float4 xv[4];
#pragma unroll
        for (int r = 0; r < 4; ++r) {
            int rr = (r < nrows) ? r : 0;
            xv[r] = ld4(xb + (size_t)rr * 64 + k4 * 4);
        }
        float w0 = Ws[(4 * k4 + 0) * 64 + c];
        float w1 = Ws[(4 * k4 + 1) * 64 + c];
        float w2 = Ws[(4 * k4 + 2) * 64 + c];
        float w3 = Ws[(4 * k4 + 3) * 64 + c];
#pragma unroll
        for (int r = 0; r < 4; ++r) {
            acc[r] = fmaf(xv[r].x, w0, acc[r]);
            acc[r] = fmaf(xv[r].y, w1, acc[r]);
            acc[r] = fmaf(xv[r].z, w2, acc[r]);
            acc[r] = fmaf(xv[r].w, w3, acc[r]);
        }
    }

    float as_w = att_s[c];
    float ad_w = att_d[c];
#pragma unroll
    for (int r = 0; r < 4; ++r) {
        if (r >= nrows) break;
        int n = n0 + r;
        float a = acc[r];
        hout[(size_t)n * 64 + c] = __float2bfloat16(a);
        float vs = a * as_w;
        float vd = a * ad_w;
#pragma unroll
        for (int off = 1; off < C; off <<= 1) {
            vs += __shfl_xor(vs, off, 64);
            vd += __shfl_xor(vd, off, 64);
        }
        if ((c % C) == 0) {
            int hd = c / C;
            asrc[(size_t)n * H + hd] = vs;
            adst[(size_t)n * H + hd] = vd;
        }
    }
}

// ---- Edge-softmax aggregation ----------------------------------------------
// One wave per (t, dst node). Per 64-edge chunk:
//   H=8 alpha layout: lane l -> (edge l&7, head l>>3); chunk max ONCE.
//   accumulate: p via static ds_swizzle (H=8; lane' = (lane&0x18)|Q) or
//   SGPR readlane (H=1); src index via readlane -> scalar-base gather.

template <int H, bool FINAL>
__global__ __launch_bounds__(256) void gat_edge_kernel(
    const bf16* __restrict__ h_all,     // [T*N,64] bf16
    const float* __restrict__ asrc_all, // [T*N*H]
    const float* __restrict__ adst_all, // [T*N*H]
    const int* __restrict__ row,        // [N+1]
    const int* __restrict__ esrc,       // [Etot]
    const float* __restrict__ bias,     // [64]
    bf16* __restrict__ outb,            // (!FINAL) [T*N,64] bf16
    float* __restrict__ outf,           // (FINAL)  [T*N,64] f32
    int N, int BPT) {
    int tid  = threadIdx.x;
    int lane = tid & 63;
    int t  = blockIdx.x / BPT;
    int nb = blockIdx.x - t * BPT;
    int n  = nb * 4 + (tid >> 6);
    if (n >= N) return;

    const bf16*  h    = h_all    + (size_t)t * N * 64;
    const float* asrc = asrc_all + (size_t)t * N * H;
    const float* adst = adst_all + (size_t)t * N * H;

    const int head = (H == 8) ? (lane >> 3) : 0;
    float adn = adst[(size_t)n * H + head];

    int e0  = row[n];
    int deg = row[n + 1] - e0;

    float m_run = -INFINITY;
    float lsum_lane = 0.f;
    float acc0 = 0.f, acc1 = 0.f;

    for (int base = 0; base < deg; base += 64) {
        int cnt = deg - base; if (cnt > 64) cnt = 64;
        int sv = (lane < cnt) ? esrc[e0 + base + lane] : 0;

        if constexpr (H == 8) {
            // ---- alpha for all 64 edges x 8 heads: a[sub] at lane l is
            //      alpha(edge sub*8 + (l&7), head l>>3) ----
            float a[8];
#pragma unroll
            for (int sub = 0; sub < 8; ++sub) a[sub] = -INFINITY;
#pragma unroll
            for (int sub = 0; sub < 8; ++sub) {
                if (sub * 8 >= cnt) break;
                int svj = __builtin_amdgcn_ds_bpermute(((sub * 8) | (lane & 7)) << 2, sv);
                float av = asrc[(((unsigned)svj) << 3) | head];
                float tv = av + adn;
                tv = tv > 0.f ? tv : 0.2f * tv;              // leaky_relu(0.2)
                a[sub] = (sub * 8 + (lane & 7) < cnt) ? tv : -INFINITY;
            }
            // ---- chunk max per head (once) ----
            float mx = a[0];
#pragma unroll
            for (int sub = 1; sub < 8; ++sub) mx = fmaxf(mx, a[sub]);
            mx = fmaxf(mx, __shfl_xor(mx, 1, 64));
            mx = fmaxf(mx, __shfl_xor(mx, 2, 64));
            mx = fmaxf(mx, __shfl_xor(mx, 4, 64));
            float mn = fmaxf(m_run, mx);
            float sc = __expf(m_run - mn);                   // first chunk: 0
            m_run = mn;
            lsum_lane *= sc; acc0 *= sc; acc1 *= sc;
            float p[8];
#pragma unroll
            for (int sub = 0; sub < 8; ++sub) {
                p[sub] = __expf(a[sub] - mn);                // invalid -> 0
                lsum_lane += p[sub];
            }
            // ---- accumulate: lane = output feature (head lane>>3) ----
#pragma unroll
            for (int sub = 0; sub < 8; ++sub) {
                if (sub * 8 >= cnt) break;
                unsigned pu = __float_as_uint(p[sub]);
#define ACC_EDGE(Q)                                                            \
    {                                                                          \
        float pj = __uint_as_float(                                            \
            __builtin_amdgcn_ds_swizzle(pu, ((Q) << 5) | 0x18));               \
        unsigned sj = (unsigned)__builtin_amdgcn_readlane(sv, sub * 8 + (Q));  \
        float hvf = bf2f(*(const unsigned short*)(h + (((size_t)sj << 6) | lane))); \
        if ((Q) & 1) acc1 = fmaf(pj, hvf, acc1);                               \
        else         acc0 = fmaf(pj, hvf, acc0);                               \
    }
                ACC_EDGE(0) ACC_EDGE(1) ACC_EDGE(2) ACC_EDGE(3)
                ACC_EDGE(4) ACC_EDGE(5) ACC_EDGE(6) ACC_EDGE(7)
#undef ACC_EDGE
            }
        } else {
            // ---- H == 1: alpha at lane = edge ----
            float av = asrc[(unsigned)sv];
            float tv = av + adn;
            tv = tv > 0.f ? tv : 0.2f * tv;                  // leaky_relu(0.2)
            float a0 = (lane < cnt) ? tv : -INFINITY;
            float mx = a0;
#pragma unroll
            for (int o = 1; o < 64; o <<= 1) mx = fmaxf(mx, __shfl_xor(mx, o, 64));
            float mn = fmaxf(m_run, mx);
            float sc = __expf(m_run - mn);
            m_run = mn;
            lsum_lane *= sc; acc0 *= sc; acc1 *= sc;
            float p0 = __expf(a0 - mn);                      // invalid -> 0
            lsum_lane += p0;
            for (int j0 = 0; j0 < cnt; j0 += 8) {
#pragma unroll
                for (int q = 0; q < 8; ++q) {
                    int j = j0 + q;                          // j>=cnt: p==0, safe
                    float pj = __uint_as_float(
                        __builtin_amdgcn_readlane(__float_as_uint(p0), j));
                    unsigned sj = (unsigned)__builtin_amdgcn_readlane(sv, j);
                    float hvf = bf2f(*(const unsigned short*)(h + (((size_t)sj << 6) | lane)));
                    if (q & 1) acc1 = fmaf(pj, hvf, acc1);
                    else       acc0 = fmaf(pj, hvf, acc0);
                }
            }
        }
    }

    float lsum;
    if constexpr (H == 8) {
        float ls = lsum_lane;
        ls += __shfl_xor(ls, 1, 64);
        ls += __shfl_xor(ls, 2, 64);
        ls += __shfl_xor(ls, 4, 64);
        lsum = ls;                                           // uniform per 8-group
    } else {
        float ls = lsum_lane;
#pragma unroll
        for (int o = 1; o < 64; o <<= 1) ls += __shfl_xor(ls, o, 64);
        lsum = ls;
    }

    float v = (acc0 + acc1) / (lsum + 1e-16f) + bias[lane];
    size_t oidx = ((size_t)t * N + n) * 64 + lane;
    if (!FINAL) {
        float y = v > 0.f ? v : expm1f(v);                   // ELU
        outb[oidx] = __float2bfloat16(y);
    } else {
        float mx = v;
#pragma unroll
        for (int off = 1; off < 64; off <<= 1) mx = fmaxf(mx, __shfl_xor(mx, off, 64));
        float ex = __expf(v - mx);
        float sm = ex;
#pragma unroll
        for (int off = 1; off < 64; off <<= 1) sm += __shfl_xor(sm, off, 64);
        outf[oidx] = (v - mx) - __logf(sm);
    }
}

// ---------------------------------------------------------------------------

extern "C" void kernel_launch(void* const* d_in, const int* in_sizes, int n_in,
                              void* d_out, int out_size, void* d_ws, size_t ws_size,
                              hipStream_t stream) {
    const float* x        = (const float*)d_in[0];   // [T,N,64]
    const int*   eidx     = (const int*)d_in[1];     // [2,E]
    const float* W1       = (const float*)d_in[2];
    const float* att_src1 = (const float*)d_in[3];
    const float* att_dst1 = (const float*)d_in[4];
    const float* bias1    = (const float*)d_in[5];
    const float* W2       = (const float*)d_in[6];
    const float* att_src2 = (const float*)d_in[7];
    const float* att_dst2 = (const float*)d_in[8];
    const float* bias2    = (const float*)d_in[9];
    float* dout = (float*)d_out;

    const int N = 50000;
    const int F = 64;
    const int E = in_sizes[1] / 2;
    const int T = in_sizes[0] / (N * F);
    const int NT = T * N;
    const int Etot = E + N;
    const int BPT = (N + 3) / 4;          // blocks per timestep (4 nodes/block)

    const int* srcs = eidx;
    const int* dsts = eidx + E;

    char* ws = (char*)d_ws;
    size_t off = 0;
    auto carve = [&](size_t bytes) -> void* {
        void* p = ws + off;
        off = (off + bytes + 255) & ~(size_t)255;
        return p;
    };
    bf16*  h_all  = (bf16*)carve((size_t)NT * 64 * sizeof(bf16));
    bf16*  y1_all = (bf16*)carve((size_t)NT * 64 * sizeof(bf16));
    float* asrc   = (float*)carve((size_t)NT * 8 * sizeof(float));
    float* adst   = (float*)carve((size_t)NT * 8 * sizeof(float));
    int*   rowp   = (int*)carve((size_t)(N + 1) * sizeof(int));
    int*   cnt    = (int*)carve((size_t)N * sizeof(int));
    int*   cur    = (int*)carve((size_t)N * sizeof(int));
    int*   esrc   = (int*)carve((size_t)Etot * sizeof(int));
    bool batched = (off <= ws_size);

    if (batched) {
        init_cnt_kernel<<<(N + 255) / 256, 256, 0, stream>>>(cnt, N);
        count_edges_kernel<<<(E + 255) / 256, 256, 0, stream>>>(dsts, cnt, E);
        scan_kernel<<<1, 1024, 0, stream>>>(cnt, rowp, cur, N);
        fill_csr_kernel<<<(E + N + 255) / 256, 256, 0, stream>>>(srcs, dsts, cur, esrc, E, N);

        int gemm_grid = (NT + 15) / 16;
        int edge_grid = BPT * T;
        gemm_att_kernel<float, 8, 8><<<gemm_grid, 256, 0, stream>>>(
            x, W1, att_src1, att_dst1, h_all, asrc, adst, NT);
        gat_edge_kernel<8, false><<<edge_grid, 256, 0, stream>>>(
            h_all, asrc, adst, rowp, esrc, bias1, y1_all, nullptr, N, BPT);
        gemm_att_kernel<bf16, 1, 64><<<gemm_grid, 256, 0, stream>>>(
            y1_all, W2, att_src2, att_dst2, h_all, asrc, adst, NT);
        gat_edge_kernel<1, true><<<edge_grid, 256, 0, stream>>>(
            h_all, asrc, adst, rowp, esrc, bias2, nullptr, dout, N, BPT);
    } else {
        // fallback: per-timestep with small buffers (re-carve)
        off = 0;
        bf16*  h1  = (bf16*)carve((size_t)N * 64 * sizeof(bf16));
        bf16*  y1  = (bf16*)carve((size_t)N * 64 * sizeof(bf16));
        float* as1 = (float*)carve((size_t)N * 8 * sizeof(float));
        float* ad1 = (float*)carve((size_t)N * 8 * sizeof(float));
        int*   rp  = (int*)carve((size_t)(N + 1) * sizeof(int));
        int*   cn  = (int*)carve((size_t)N * sizeof(int));
        int*   cu  = (int*)carve((size_t)N * sizeof(int));
        int*   es  = (int*)carve((size_t)Etot * sizeof(int));
        init_cnt_kernel<<<(N + 255) / 256, 256, 0, stream>>>(cn, N);
        count_edges_kernel<<<(E + 255) / 256, 256, 0, stream>>>(dsts, cn, E);
        scan_kernel<<<1, 1024, 0, stream>>>(cn, rp, cu, N);
        fill_csr_kernel<<<(E + N + 255) / 256, 256, 0, stream>>>(srcs, dsts, cu, es, E, N);
        int gemm_grid = (N + 15) / 16;
        for (int t = 0; t < T; ++t) {
            const float* xt = x + (size_t)t * N * F;
            float* ot = dout + (size_t)t * N * F;
            gemm_att_kernel<float, 8, 8><<<gemm_grid, 256, 0, stream>>>(
                xt, W1, att_src1, att_dst1, h1, as1, ad1, N);
            gat_edge_kernel<8, false><<<(N + 3) / 4, 256, 0, stream>>>(
                h1, as1, ad1, rp, es, bias1, y1, nullptr, N, (N + 3) / 4);
            gemm_att_kernel<bf16, 1, 64><<<gemm_grid, 256, 0, stream>>>(
                y1, W2, att_src2, att_dst2, h1, as1, ad1, N);
            gat_edge_kernel<1, true><<<(N + 3) / 4, 256, 0, stream>>>(
                h1, as1, ad1, rp, es, bias2, nullptr, ot, N, (N + 3) / 4);
        }
    }
}